// Round 1
// baseline (1966.657 us; speedup 1.0000x reference)
//
#include <hip/hip_runtime.h>
#include <math.h>

#define N_NODES 100000
#define N_EDGES 1600000
#define G_GRAPHS 256
#define IN_F 128
#define H_F 64

// ---------------------------------------------------------------------------
// 1. Degree accumulation: deg_out[src]++ , deg_in[dst]++
// ---------------------------------------------------------------------------
__global__ __launch_bounds__(256) void deg_kernel(
    const int* __restrict__ src, const int* __restrict__ dst,
    float* __restrict__ deg_out, float* __restrict__ deg_in, int E) {
  int e = blockIdx.x * blockDim.x + threadIdx.x;
  if (e < E) {
    atomicAdd(&deg_out[src[e]], 1.0f);
    atomicAdd(&deg_in[dst[e]], 1.0f);
  }
}

// In-place deg -> rsqrt(max(deg,1))   (applied to 2N contiguous floats)
__global__ __launch_bounds__(256) void norm_kernel(float* __restrict__ deg, int n) {
  int i = blockIdx.x * blockDim.x + threadIdx.x;
  if (i < n) deg[i] = rsqrtf(fmaxf(deg[i], 1.0f));
}

// ---------------------------------------------------------------------------
// 2. T[i,:] = ns[i] * (X[i,:] @ W)   X:[n,K]  W:[K,64]  T:[n,64]
//    block = 256 threads, 32 nodes/block. W staged in LDS.
// ---------------------------------------------------------------------------
template <int K>
__global__ __launch_bounds__(256) void gemm_ns_kernel(
    const float* __restrict__ X, const float* __restrict__ W,
    const float* __restrict__ ns, float* __restrict__ T, int n) {
  __shared__ float Wl[K * 64];
  __shared__ float Xl[4][K];

  for (int i = threadIdx.x; i < K * 64; i += 256) Wl[i] = W[i];

  const int j  = threadIdx.x & 63;   // output feature
  const int nl = threadIdx.x >> 6;   // 0..3 node slot
  const int base = blockIdx.x * 32;

  for (int it = 0; it < 8; ++it) {
    __syncthreads();  // protect Xl reuse (and Wl on first iter)
    for (int i = threadIdx.x; i < 4 * K; i += 256) {
      int r = i / K, c = i % K;
      int nn = base + it * 4 + r;
      Xl[r][c] = (nn < n) ? X[(long long)nn * K + c] : 0.0f;
    }
    __syncthreads();
    int node = base + it * 4 + nl;
    if (node < n) {
      float acc = 0.0f;
#pragma unroll
      for (int k = 0; k < K; ++k) acc += Xl[nl][k] * Wl[k * 64 + j];
      T[(long long)node * 64 + j] = acc * ns[node];
    }
  }
}

// ---------------------------------------------------------------------------
// 3. Edge scatter: agg[dst[e], :] += T[src[e], :] * ew[e]
//    one wave (64 lanes) per edge; lane = feature.
// ---------------------------------------------------------------------------
__global__ __launch_bounds__(256) void scatter_kernel(
    const int* __restrict__ src, const int* __restrict__ dst,
    const float* __restrict__ ew, const float* __restrict__ T,
    float* __restrict__ agg, int E) {
  int id = blockIdx.x * blockDim.x + threadIdx.x;  // E*64 = 102.4M < 2^31
  int e = id >> 6;
  int j = id & 63;
  if (e < E) {
    int s = src[e], d = dst[e];
    float w = ew[e];
    atomicAdd(&agg[(long long)d * 64 + j], T[(long long)s * 64 + j] * w);
  }
}

// ---------------------------------------------------------------------------
// 4. h = relu(agg * nd + b)
// ---------------------------------------------------------------------------
__global__ __launch_bounds__(256) void finalize_kernel(
    const float* __restrict__ agg, const float* __restrict__ nd,
    const float* __restrict__ b, float* __restrict__ Hout, int n) {
  int id = blockIdx.x * blockDim.x + threadIdx.x;
  if (id < n * 64) {
    int node = id >> 6, j = id & 63;
    Hout[id] = fmaxf(fmaf(agg[id], nd[node], b[j]), 0.0f);
  }
}

// ---------------------------------------------------------------------------
// 5. Pool: pooled[gid[n],:] += h[n,:] ; counts[gid[n]]++
// ---------------------------------------------------------------------------
__global__ __launch_bounds__(256) void pool_kernel(
    const float* __restrict__ Hin, const int* __restrict__ gid,
    float* __restrict__ pooled, float* __restrict__ counts, int n) {
  int id = blockIdx.x * blockDim.x + threadIdx.x;
  if (id < n * 64) {
    int node = id >> 6, j = id & 63;
    int g = gid[node];
    atomicAdd(&pooled[g * 64 + j], Hin[id]);
    if (j == 0) atomicAdd(&counts[g], 1.0f);
  }
}

// ---------------------------------------------------------------------------
// 6. MLP head: 64 -> 16 -> 8 -> 1, sigmoid. One thread per graph.
// ---------------------------------------------------------------------------
__global__ __launch_bounds__(256) void mlp_kernel(
    const float* __restrict__ pooled, const float* __restrict__ counts,
    const float* __restrict__ Dw1, const float* __restrict__ Db1,
    const float* __restrict__ Dw2, const float* __restrict__ Db2,
    const float* __restrict__ Dw3, const float* __restrict__ Db3,
    float* __restrict__ out) {
  int g = blockIdx.x * blockDim.x + threadIdx.x;
  if (g < G_GRAPHS) {
    float inv = 1.0f / fmaxf(counts[g], 1.0f);
    float p[64];
#pragma unroll
    for (int k = 0; k < 64; ++k) p[k] = pooled[g * 64 + k] * inv;
    float h1[16];
#pragma unroll
    for (int o = 0; o < 16; ++o) {
      float a = Db1[o];
      for (int k = 0; k < 64; ++k) a = fmaf(p[k], Dw1[k * 16 + o], a);
      h1[o] = fmaxf(a, 0.0f);
    }
    float h2[8];
#pragma unroll
    for (int o = 0; o < 8; ++o) {
      float a = Db2[o];
      for (int k = 0; k < 16; ++k) a = fmaf(h1[k], Dw2[k * 8 + o], a);
      h2[o] = fmaxf(a, 0.0f);
    }
    float a = Db3[0];
#pragma unroll
    for (int k = 0; k < 8; ++k) a = fmaf(h2[k], Dw3[k], a);
    out[g] = 1.0f / (1.0f + expf(-a));
  }
}

// ---------------------------------------------------------------------------
extern "C" void kernel_launch(void* const* d_in, const int* in_sizes, int n_in,
                              void* d_out, int out_size, void* d_ws, size_t ws_size,
                              hipStream_t stream) {
  const float* x   = (const float*)d_in[0];
  const int*   src = (const int*)  d_in[1];
  const int*   dst = (const int*)  d_in[2];
  const float* ew  = (const float*)d_in[3];
  const int*   gid = (const int*)  d_in[4];
  const float* W1  = (const float*)d_in[5];
  const float* b1  = (const float*)d_in[6];
  const float* W2  = (const float*)d_in[7];
  const float* b2  = (const float*)d_in[8];
  const float* W3  = (const float*)d_in[9];
  const float* b3  = (const float*)d_in[10];
  const float* Dw1 = (const float*)d_in[11];
  const float* Db1 = (const float*)d_in[12];
  const float* Dw2 = (const float*)d_in[13];
  const float* Db2 = (const float*)d_in[14];
  const float* Dw3 = (const float*)d_in[15];
  const float* Db3 = (const float*)d_in[16];
  float* out = (float*)d_out;

  // workspace layout (floats)
  char* ws = (char*)d_ws;
  float* bufA   = (float*)ws;                        // N*64
  float* bufB   = bufA + (size_t)N_NODES * 64;       // N*64
  float* ns     = bufB + (size_t)N_NODES * 64;       // N
  float* nd     = ns + N_NODES;                      // N   (contiguous with ns)
  float* pooled = nd + N_NODES;                      // G*64
  float* counts = pooled + G_GRAPHS * 64;            // G   (contiguous with pooled)

  const int NB_E    = (N_EDGES + 255) / 256;
  const int NB_2N   = (2 * N_NODES + 255) / 256;
  const int NB_GEMM = (N_NODES + 31) / 32;
  const int NB_SCAT = (N_EDGES * 64) / 256;          // exact: 1.6M*64 % 256 == 0
  const int NB_NF   = (N_NODES * 64 + 255) / 256;

  // degrees -> norms
  hipMemsetAsync(ns, 0, 2ull * N_NODES * sizeof(float), stream);
  deg_kernel<<<NB_E, 256, 0, stream>>>(src, dst, ns, nd, N_EDGES);
  norm_kernel<<<NB_2N, 256, 0, stream>>>(ns, 2 * N_NODES);

  // ---- layer 1: x(128) -> bufA(T1) -> scatter into bufB -> h1 in bufA
  gemm_ns_kernel<IN_F><<<NB_GEMM, 256, 0, stream>>>(x, W1, ns, bufA, N_NODES);
  hipMemsetAsync(bufB, 0, (size_t)N_NODES * 64 * sizeof(float), stream);
  scatter_kernel<<<NB_SCAT, 256, 0, stream>>>(src, dst, ew, bufA, bufB, N_EDGES);
  finalize_kernel<<<NB_NF, 256, 0, stream>>>(bufB, nd, b1, bufA, N_NODES);

  // ---- layer 2: bufA -> bufB(T2) -> scatter into bufA -> h2 in bufB
  gemm_ns_kernel<H_F><<<NB_GEMM, 256, 0, stream>>>(bufA, W2, ns, bufB, N_NODES);
  hipMemsetAsync(bufA, 0, (size_t)N_NODES * 64 * sizeof(float), stream);
  scatter_kernel<<<NB_SCAT, 256, 0, stream>>>(src, dst, ew, bufB, bufA, N_EDGES);
  finalize_kernel<<<NB_NF, 256, 0, stream>>>(bufA, nd, b2, bufB, N_NODES);

  // ---- layer 3: bufB -> bufA(T3) -> scatter into bufB -> h3 in bufA
  gemm_ns_kernel<H_F><<<NB_GEMM, 256, 0, stream>>>(bufB, W3, ns, bufA, N_NODES);
  hipMemsetAsync(bufB, 0, (size_t)N_NODES * 64 * sizeof(float), stream);
  scatter_kernel<<<NB_SCAT, 256, 0, stream>>>(src, dst, ew, bufA, bufB, N_EDGES);
  finalize_kernel<<<NB_NF, 256, 0, stream>>>(bufB, nd, b3, bufA, N_NODES);

  // ---- pooling + MLP head
  hipMemsetAsync(pooled, 0, (size_t)(G_GRAPHS * 64 + G_GRAPHS) * sizeof(float), stream);
  pool_kernel<<<NB_NF, 256, 0, stream>>>(bufA, gid, pooled, counts, N_NODES);
  mlp_kernel<<<1, 256, 0, stream>>>(pooled, counts, Dw1, Db1, Dw2, Db2, Dw3, Db3, out);
}

// Round 2
// 1070.035 us; speedup vs baseline: 1.8379x; 1.8379x over previous
//
#include <hip/hip_runtime.h>
#include <math.h>

#define N_NODES 100000
#define N_EDGES 1600000
#define G_GRAPHS 256
#define IN_F 128
#define H_F 64

#define SCAN_CH 1024        // elements per scan block
#define PWAVES 1024         // waves for segmented pool
#define PCHUNK ((N_NODES + PWAVES - 1) / PWAVES)

// ---------------------------------------------------------------------------
// 1. Integer degree histograms
// ---------------------------------------------------------------------------
__global__ __launch_bounds__(256) void hist_kernel(
    const int* __restrict__ src, const int* __restrict__ dst,
    int* __restrict__ cnt_out, int* __restrict__ cnt_in, int E) {
  int e = blockIdx.x * blockDim.x + threadIdx.x;
  if (e < E) {
    atomicAdd(&cnt_out[src[e]], 1);
    atomicAdd(&cnt_in[dst[e]], 1);
  }
}

// ns/nd = rsqrt(max(deg,1))
__global__ __launch_bounds__(256) void norm_kernel(
    const int* __restrict__ cnt_out, const int* __restrict__ cnt_in,
    float* __restrict__ ns, float* __restrict__ nd, int n) {
  int i = blockIdx.x * blockDim.x + threadIdx.x;
  if (i < n) {
    ns[i] = rsqrtf(fmaxf((float)cnt_out[i], 1.0f));
    nd[i] = rsqrtf(fmaxf((float)cnt_in[i], 1.0f));
  }
}

// ---------------------------------------------------------------------------
// 2. Exclusive scan of cnt_in -> row_ptr (3-kernel: per-block, block sums, add)
// ---------------------------------------------------------------------------
__global__ __launch_bounds__(256) void scanA_kernel(
    const int* __restrict__ in, int* __restrict__ out, int* __restrict__ bsums, int n) {
  __shared__ int ts[256];
  const int tid = threadIdx.x;
  const int base = blockIdx.x * SCAN_CH + tid * 4;
  int v[4], pre[4], s = 0;
#pragma unroll
  for (int k = 0; k < 4; ++k) {
    v[k] = (base + k < n) ? in[base + k] : 0;
    pre[k] = s;
    s += v[k];
  }
  ts[tid] = s;
  __syncthreads();
  for (int off = 1; off < 256; off <<= 1) {
    int t = (tid >= off) ? ts[tid - off] : 0;
    __syncthreads();
    ts[tid] += t;
    __syncthreads();
  }
  int excl = (tid == 0) ? 0 : ts[tid - 1];
#pragma unroll
  for (int k = 0; k < 4; ++k)
    if (base + k < n) out[base + k] = excl + pre[k];
  if (tid == 255) bsums[blockIdx.x] = ts[255];
}

__global__ __launch_bounds__(256) void scanB_kernel(int* __restrict__ bsums, int nb) {
  __shared__ int ts[256];
  const int tid = threadIdx.x;
  ts[tid] = (tid < nb) ? bsums[tid] : 0;
  __syncthreads();
  for (int off = 1; off < 256; off <<= 1) {
    int t = (tid >= off) ? ts[tid - off] : 0;
    __syncthreads();
    ts[tid] += t;
    __syncthreads();
  }
  if (tid < nb) bsums[tid] = (tid == 0) ? 0 : ts[tid - 1];
}

__global__ __launch_bounds__(256) void scanC_kernel(
    int* __restrict__ out, const int* __restrict__ bsums, int n) {
  int i = blockIdx.x * blockDim.x + threadIdx.x;
  if (i < n) out[i] += bsums[i / SCAN_CH];
}

// ---------------------------------------------------------------------------
// 3. Edge placement into CSR (dst-major)
// ---------------------------------------------------------------------------
__global__ __launch_bounds__(256) void place_kernel(
    const int* __restrict__ src, const int* __restrict__ dst,
    const float* __restrict__ ew, const int* __restrict__ row_ptr,
    int* __restrict__ cursor, int* __restrict__ csr_src,
    float* __restrict__ csr_w, int E) {
  int e = blockIdx.x * blockDim.x + threadIdx.x;
  if (e < E) {
    int d = dst[e];
    int slot = row_ptr[d] + atomicAdd(&cursor[d], 1);
    csr_src[slot] = src[e];
    csr_w[slot] = ew[e];
  }
}

// ---------------------------------------------------------------------------
// 4. T[i,:] = ns[i] * (X[i,:] @ W)   X:[n,K]  W:[K,64]  T:[n,64]
// ---------------------------------------------------------------------------
template <int K>
__global__ __launch_bounds__(256) void gemm_ns_kernel(
    const float* __restrict__ X, const float* __restrict__ W,
    const float* __restrict__ ns, float* __restrict__ T, int n) {
  __shared__ float Wl[K * 64];
  __shared__ float Xl[4][K];

  for (int i = threadIdx.x; i < K * 64; i += 256) Wl[i] = W[i];

  const int j  = threadIdx.x & 63;
  const int nl = threadIdx.x >> 6;
  const int base = blockIdx.x * 32;

  for (int it = 0; it < 8; ++it) {
    __syncthreads();
    for (int i = threadIdx.x; i < 4 * K; i += 256) {
      int r = i / K, c = i % K;
      int nn = base + it * 4 + r;
      Xl[r][c] = (nn < n) ? X[(long long)nn * K + c] : 0.0f;
    }
    __syncthreads();
    int node = base + it * 4 + nl;
    if (node < n) {
      float acc = 0.0f;
#pragma unroll
      for (int k = 0; k < K; ++k) acc += Xl[nl][k] * Wl[k * 64 + j];
      T[(long long)node * 64 + j] = acc * ns[node];
    }
  }
}

// ---------------------------------------------------------------------------
// 5. CSR gather + fused finalize: H[v,:] = relu(nd[v] * sum_e T[src_e,:]*w_e + b)
//    One wave per node, lane = feature.
// ---------------------------------------------------------------------------
__global__ __launch_bounds__(256) void gather_kernel(
    const int* __restrict__ csr_src, const float* __restrict__ csr_w,
    const int* __restrict__ row_ptr, const int* __restrict__ cnt_in,
    const float* __restrict__ T, const float* __restrict__ nd,
    const float* __restrict__ b, float* __restrict__ Hout, int n) {
  int id = blockIdx.x * blockDim.x + threadIdx.x;
  int node = id >> 6, j = id & 63;
  if (node < n) {
    int start = row_ptr[node];
    int cnt = cnt_in[node];
    float acc = 0.0f;
    for (int k = 0; k < cnt; ++k) {
      int s = csr_src[start + k];
      float w = csr_w[start + k];
      acc = fmaf(T[(long long)s * 64 + j], w, acc);
    }
    Hout[(long long)node * 64 + j] = fmaxf(fmaf(acc, nd[node], b[j]), 0.0f);
  }
}

// ---------------------------------------------------------------------------
// 6. Segmented pool over sorted gid: one wave per node chunk, register acc,
//    flush atomics only at graph boundaries.
// ---------------------------------------------------------------------------
__global__ __launch_bounds__(256) void pool_seg_kernel(
    const float* __restrict__ H, const int* __restrict__ gid,
    float* __restrict__ pooled, float* __restrict__ counts, int n) {
  int wid = (blockIdx.x * blockDim.x + threadIdx.x) >> 6;
  int j = threadIdx.x & 63;
  int s = wid * PCHUNK;
  if (s >= n) return;
  int e = min(s + PCHUNK, n);
  float acc = 0.0f;
  int cur = gid[s];
  int runlen = 0;
  for (int node = s; node < e; ++node) {
    int g = gid[node];
    if (g != cur) {
      atomicAdd(&pooled[cur * 64 + j], acc);
      if (j == 0) atomicAdd(&counts[cur], (float)runlen);
      acc = 0.0f;
      runlen = 0;
      cur = g;
    }
    acc += H[(long long)node * 64 + j];
    ++runlen;
  }
  atomicAdd(&pooled[cur * 64 + j], acc);
  if (j == 0) atomicAdd(&counts[cur], (float)runlen);
}

// ---------------------------------------------------------------------------
// 7. MLP head
// ---------------------------------------------------------------------------
__global__ __launch_bounds__(256) void mlp_kernel(
    const float* __restrict__ pooled, const float* __restrict__ counts,
    const float* __restrict__ Dw1, const float* __restrict__ Db1,
    const float* __restrict__ Dw2, const float* __restrict__ Db2,
    const float* __restrict__ Dw3, const float* __restrict__ Db3,
    float* __restrict__ out) {
  int g = blockIdx.x * blockDim.x + threadIdx.x;
  if (g < G_GRAPHS) {
    float inv = 1.0f / fmaxf(counts[g], 1.0f);
    float p[64];
#pragma unroll
    for (int k = 0; k < 64; ++k) p[k] = pooled[g * 64 + k] * inv;
    float h1[16];
#pragma unroll
    for (int o = 0; o < 16; ++o) {
      float a = Db1[o];
      for (int k = 0; k < 64; ++k) a = fmaf(p[k], Dw1[k * 16 + o], a);
      h1[o] = fmaxf(a, 0.0f);
    }
    float h2[8];
#pragma unroll
    for (int o = 0; o < 8; ++o) {
      float a = Db2[o];
      for (int k = 0; k < 16; ++k) a = fmaf(h1[k], Dw2[k * 8 + o], a);
      h2[o] = fmaxf(a, 0.0f);
    }
    float a = Db3[0];
#pragma unroll
    for (int k = 0; k < 8; ++k) a = fmaf(h2[k], Dw3[k], a);
    out[g] = 1.0f / (1.0f + expf(-a));
  }
}

// ---------------------------------------------------------------------------
extern "C" void kernel_launch(void* const* d_in, const int* in_sizes, int n_in,
                              void* d_out, int out_size, void* d_ws, size_t ws_size,
                              hipStream_t stream) {
  const float* x   = (const float*)d_in[0];
  const int*   src = (const int*)  d_in[1];
  const int*   dst = (const int*)  d_in[2];
  const float* ew  = (const float*)d_in[3];
  const int*   gid = (const int*)  d_in[4];
  const float* W1  = (const float*)d_in[5];
  const float* b1  = (const float*)d_in[6];
  const float* W2  = (const float*)d_in[7];
  const float* b2  = (const float*)d_in[8];
  const float* W3  = (const float*)d_in[9];
  const float* b3  = (const float*)d_in[10];
  const float* Dw1 = (const float*)d_in[11];
  const float* Db1 = (const float*)d_in[12];
  const float* Dw2 = (const float*)d_in[13];
  const float* Db2 = (const float*)d_in[14];
  const float* Dw3 = (const float*)d_in[15];
  const float* Db3 = (const float*)d_in[16];
  float* out = (float*)d_out;

  // workspace layout
  char* ws = (char*)d_ws;
  float* bufA    = (float*)ws;                         // N*64 (T)
  float* bufB    = bufA + (size_t)N_NODES * 64;        // N*64 (H)
  float* ns      = bufB + (size_t)N_NODES * 64;        // N
  float* nd      = ns + N_NODES;                       // N
  float* pooled  = nd + N_NODES;                       // G*64
  float* counts  = pooled + G_GRAPHS * 64;             // G
  int*   cnt_out = (int*)(counts + G_GRAPHS);          // N (reused as cursor)
  int*   cnt_in  = cnt_out + N_NODES;                  // N
  int*   row_ptr = cnt_in + N_NODES;                   // N
  int*   bsums   = row_ptr + N_NODES;                  // 128
  int*   csr_src = bsums + 128;                        // E
  float* csr_w   = (float*)(csr_src + N_EDGES);        // E

  const int NB_E    = (N_EDGES + 255) / 256;
  const int NB_N    = (N_NODES + 255) / 256;
  const int NB_SCAN = (N_NODES + SCAN_CH - 1) / SCAN_CH;   // 98
  const int NB_GEMM = (N_NODES + 31) / 32;
  const int NB_NF   = (N_NODES * 64 + 255) / 256;
  const int NB_POOL = (PWAVES * 64) / 256;

  // ---- degrees, norms, CSR build
  hipMemsetAsync(cnt_out, 0, 2ull * N_NODES * sizeof(int), stream);
  hist_kernel<<<NB_E, 256, 0, stream>>>(src, dst, cnt_out, cnt_in, N_EDGES);
  norm_kernel<<<NB_N, 256, 0, stream>>>(cnt_out, cnt_in, ns, nd, N_NODES);
  scanA_kernel<<<NB_SCAN, 256, 0, stream>>>(cnt_in, row_ptr, bsums, N_NODES);
  scanB_kernel<<<1, 256, 0, stream>>>(bsums, NB_SCAN);
  scanC_kernel<<<NB_N, 256, 0, stream>>>(row_ptr, bsums, N_NODES);
  hipMemsetAsync(cnt_out, 0, (size_t)N_NODES * sizeof(int), stream);  // cursor
  place_kernel<<<NB_E, 256, 0, stream>>>(src, dst, ew, row_ptr, cnt_out,
                                         csr_src, csr_w, N_EDGES);

  // ---- layer 1: x -> T(bufA) -> H(bufB)
  gemm_ns_kernel<IN_F><<<NB_GEMM, 256, 0, stream>>>(x, W1, ns, bufA, N_NODES);
  gather_kernel<<<NB_NF, 256, 0, stream>>>(csr_src, csr_w, row_ptr, cnt_in,
                                           bufA, nd, b1, bufB, N_NODES);
  // ---- layer 2: H(bufB) -> T(bufA) -> H(bufB)
  gemm_ns_kernel<H_F><<<NB_GEMM, 256, 0, stream>>>(bufB, W2, ns, bufA, N_NODES);
  gather_kernel<<<NB_NF, 256, 0, stream>>>(csr_src, csr_w, row_ptr, cnt_in,
                                           bufA, nd, b2, bufB, N_NODES);
  // ---- layer 3
  gemm_ns_kernel<H_F><<<NB_GEMM, 256, 0, stream>>>(bufB, W3, ns, bufA, N_NODES);
  gather_kernel<<<NB_NF, 256, 0, stream>>>(csr_src, csr_w, row_ptr, cnt_in,
                                           bufA, nd, b3, bufB, N_NODES);

  // ---- pool + MLP
  hipMemsetAsync(pooled, 0, (size_t)(G_GRAPHS * 64 + G_GRAPHS) * sizeof(float), stream);
  pool_seg_kernel<<<NB_POOL, 256, 0, stream>>>(bufB, gid, pooled, counts, N_NODES);
  mlp_kernel<<<1, 256, 0, stream>>>(pooled, counts, Dw1, Db1, Dw2, Db2, Dw3, Db3, out);
}

// Round 3
// 825.801 us; speedup vs baseline: 2.3815x; 1.2958x over previous
//
#include <hip/hip_runtime.h>
#include <math.h>

#define N_NODES 100000
#define N_EDGES 1600000
#define G_GRAPHS 256
#define IN_F 128
#define H_F 64

#define SCAN_CH 1024
#define PWAVES 1024
#define PCHUNK ((N_NODES + PWAVES - 1) / PWAVES)

typedef unsigned int uint_t;
typedef unsigned short ushort_t;

__device__ __forceinline__ ushort_t f2bf(float f) {  // round-to-nearest-even
  uint_t u = __float_as_uint(f);
  uint_t r = (u + 0x7fffu + ((u >> 16) & 1u)) >> 16;
  return (ushort_t)r;
}
__device__ __forceinline__ float bflo(uint_t u) { return __uint_as_float(u << 16); }
__device__ __forceinline__ float bfhi(uint_t u) { return __uint_as_float(u & 0xffff0000u); }

// ---------------------------------------------------------------------------
// 1. Integer degree histograms
// ---------------------------------------------------------------------------
__global__ __launch_bounds__(256) void hist_kernel(
    const int* __restrict__ src, const int* __restrict__ dst,
    int* __restrict__ cnt_out, int* __restrict__ cnt_in, int E) {
  int e = blockIdx.x * blockDim.x + threadIdx.x;
  if (e < E) {
    atomicAdd(&cnt_out[src[e]], 1);
    atomicAdd(&cnt_in[dst[e]], 1);
  }
}

__global__ __launch_bounds__(256) void norm_kernel(
    const int* __restrict__ cnt_out, const int* __restrict__ cnt_in,
    float* __restrict__ ns, float* __restrict__ nd, int n) {
  int i = blockIdx.x * blockDim.x + threadIdx.x;
  if (i < n) {
    ns[i] = rsqrtf(fmaxf((float)cnt_out[i], 1.0f));
    nd[i] = rsqrtf(fmaxf((float)cnt_in[i], 1.0f));
  }
}

// ---------------------------------------------------------------------------
// 2. Exclusive scan of cnt_in -> row_ptr
// ---------------------------------------------------------------------------
__global__ __launch_bounds__(256) void scanA_kernel(
    const int* __restrict__ in, int* __restrict__ out, int* __restrict__ bsums, int n) {
  __shared__ int ts[256];
  const int tid = threadIdx.x;
  const int base = blockIdx.x * SCAN_CH + tid * 4;
  int v[4], pre[4], s = 0;
#pragma unroll
  for (int k = 0; k < 4; ++k) {
    v[k] = (base + k < n) ? in[base + k] : 0;
    pre[k] = s;
    s += v[k];
  }
  ts[tid] = s;
  __syncthreads();
  for (int off = 1; off < 256; off <<= 1) {
    int t = (tid >= off) ? ts[tid - off] : 0;
    __syncthreads();
    ts[tid] += t;
    __syncthreads();
  }
  int excl = (tid == 0) ? 0 : ts[tid - 1];
#pragma unroll
  for (int k = 0; k < 4; ++k)
    if (base + k < n) out[base + k] = excl + pre[k];
  if (tid == 255) bsums[blockIdx.x] = ts[255];
}

__global__ __launch_bounds__(256) void scanB_kernel(int* __restrict__ bsums, int nb) {
  __shared__ int ts[256];
  const int tid = threadIdx.x;
  ts[tid] = (tid < nb) ? bsums[tid] : 0;
  __syncthreads();
  for (int off = 1; off < 256; off <<= 1) {
    int t = (tid >= off) ? ts[tid - off] : 0;
    __syncthreads();
    ts[tid] += t;
    __syncthreads();
  }
  if (tid < nb) bsums[tid] = (tid == 0) ? 0 : ts[tid - 1];
}

__global__ __launch_bounds__(256) void scanC_kernel(
    int* __restrict__ out, const int* __restrict__ bsums, int n) {
  int i = blockIdx.x * blockDim.x + threadIdx.x;
  if (i < n) out[i] += bsums[i / SCAN_CH];
}

// ---------------------------------------------------------------------------
// 3. Edge placement into CSR (dst-major), fused (src, weight) uint2
// ---------------------------------------------------------------------------
__global__ __launch_bounds__(256) void place_kernel(
    const int* __restrict__ src, const int* __restrict__ dst,
    const float* __restrict__ ew, const int* __restrict__ row_ptr,
    int* __restrict__ cursor, uint2* __restrict__ csr, int E) {
  int e = blockIdx.x * blockDim.x + threadIdx.x;
  if (e < E) {
    int d = dst[e];
    int slot = row_ptr[d] + atomicAdd(&cursor[d], 1);
    csr[slot] = make_uint2((uint_t)src[e], __float_as_uint(ew[e]));
  }
}

// ---------------------------------------------------------------------------
// 4. GEMM: T[i,:] = bf16(ns[i] * (X[i,:] @ W))   32 nodes/block, 8 out/thread
// ---------------------------------------------------------------------------
template <int K, bool BF16IN>
__global__ __launch_bounds__(256) void gemm_kernel(
    const void* __restrict__ Xin, const float* __restrict__ W,
    const float* __restrict__ ns, ushort_t* __restrict__ T, int n) {
  __shared__ float Wl[K * 64];
  __shared__ float Xl[32][K];
  const int tid = threadIdx.x;
  const int base = blockIdx.x * 32;

  // stage W (float4)
  {
    const float4* W4 = (const float4*)W;
    for (int i = tid; i < K * 16; i += 256) ((float4*)Wl)[i] = W4[i];
  }
  // stage X (convert to fp32 in LDS)
  if (BF16IN) {
    const uint_t* Xg = (const uint_t*)Xin;  // 2 bf16 per uint, row stride K/2
    for (int i = tid; i < 32 * (K / 2); i += 256) {
      int r = i / (K / 2), c = i % (K / 2);
      int nn = base + r;
      uint_t u = (nn < n) ? Xg[(size_t)nn * (K / 2) + c] : 0u;
      Xl[r][2 * c]     = bflo(u);
      Xl[r][2 * c + 1] = bfhi(u);
    }
  } else {
    const float4* Xg = (const float4*)Xin;  // row stride K/4
    for (int i = tid; i < 32 * (K / 4); i += 256) {
      int r = i / (K / 4), c = i % (K / 4);
      int nn = base + r;
      float4 v = make_float4(0.f, 0.f, 0.f, 0.f);
      if (nn < n) v = Xg[(size_t)nn * (K / 4) + c];
      Xl[r][4 * c] = v.x; Xl[r][4 * c + 1] = v.y;
      Xl[r][4 * c + 2] = v.z; Xl[r][4 * c + 3] = v.w;
    }
  }
  __syncthreads();

  const int j = tid & 63;
  const int q = tid >> 6;
  float acc[8] = {0, 0, 0, 0, 0, 0, 0, 0};
  for (int k = 0; k < K; k += 4) {
    float w0 = Wl[k * 64 + j];
    float w1 = Wl[(k + 1) * 64 + j];
    float w2 = Wl[(k + 2) * 64 + j];
    float w3 = Wl[(k + 3) * 64 + j];
#pragma unroll
    for (int r = 0; r < 8; ++r) {
      float4 x = *(const float4*)&Xl[q * 8 + r][k];
      acc[r] = fmaf(x.x, w0, fmaf(x.y, w1, fmaf(x.z, w2, fmaf(x.w, w3, acc[r]))));
    }
  }
#pragma unroll
  for (int r = 0; r < 8; ++r) {
    int node = base + q * 8 + r;
    if (node < n) T[(size_t)node * 64 + j] = f2bf(acc[r] * ns[node]);
  }
}

// ---------------------------------------------------------------------------
// 5. CSR gather (bf16 T), 8 edges in flight per wave-iteration.
//    lane: g = lane>>3 (edge slot), l = lane&7 (feature octet).
// ---------------------------------------------------------------------------
__global__ __launch_bounds__(256) void gather_kernel(
    const uint2* __restrict__ csr, const int* __restrict__ row_ptr,
    const int* __restrict__ cnt_in, const ushort_t* __restrict__ T,
    const float* __restrict__ nd, const float* __restrict__ b,
    ushort_t* __restrict__ H, int n) {
  int id = blockIdx.x * blockDim.x + threadIdx.x;
  int v = id >> 6;
  if (v >= n) return;
  const int lane = threadIdx.x & 63;
  const int g = lane >> 3, l = lane & 7;
  const int start = row_ptr[v];
  const int cnt = cnt_in[v];

  float acc[8] = {0, 0, 0, 0, 0, 0, 0, 0};
  for (int k = 0; k < cnt; k += 8) {
    int idx = k + g;
    uint2 e = csr[start + min(idx, cnt - 1)];
    float w = (idx < cnt) ? __uint_as_float(e.y) : 0.0f;
    uint4 p = *((const uint4*)(T + (size_t)e.x * 64) + l);
    acc[0] = fmaf(bflo(p.x), w, acc[0]);
    acc[1] = fmaf(bfhi(p.x), w, acc[1]);
    acc[2] = fmaf(bflo(p.y), w, acc[2]);
    acc[3] = fmaf(bfhi(p.y), w, acc[3]);
    acc[4] = fmaf(bflo(p.z), w, acc[4]);
    acc[5] = fmaf(bfhi(p.z), w, acc[5]);
    acc[6] = fmaf(bflo(p.w), w, acc[6]);
    acc[7] = fmaf(bfhi(p.w), w, acc[7]);
  }
  // butterfly reduce across the 8 edge-groups
#pragma unroll
  for (int off = 8; off < 64; off <<= 1) {
#pragma unroll
    for (int i = 0; i < 8; ++i) acc[i] += __shfl_xor(acc[i], off, 64);
  }
  if (g == 0) {
    float ndv = nd[v];
    float4 b0 = *(const float4*)&b[l * 8];
    float4 b1 = *(const float4*)&b[l * 8 + 4];
    uint4 o;
    o.x = (uint_t)f2bf(fmaxf(fmaf(acc[0], ndv, b0.x), 0.f)) |
          ((uint_t)f2bf(fmaxf(fmaf(acc[1], ndv, b0.y), 0.f)) << 16);
    o.y = (uint_t)f2bf(fmaxf(fmaf(acc[2], ndv, b0.z), 0.f)) |
          ((uint_t)f2bf(fmaxf(fmaf(acc[3], ndv, b0.w), 0.f)) << 16);
    o.z = (uint_t)f2bf(fmaxf(fmaf(acc[4], ndv, b1.x), 0.f)) |
          ((uint_t)f2bf(fmaxf(fmaf(acc[5], ndv, b1.y), 0.f)) << 16);
    o.w = (uint_t)f2bf(fmaxf(fmaf(acc[6], ndv, b1.z), 0.f)) |
          ((uint_t)f2bf(fmaxf(fmaf(acc[7], ndv, b1.w), 0.f)) << 16);
    *((uint4*)(H + (size_t)v * 64) + l) = o;
  }
}

// ---------------------------------------------------------------------------
// 6. Segmented pool over sorted gid (bf16 H)
// ---------------------------------------------------------------------------
__global__ __launch_bounds__(256) void pool_seg_kernel(
    const ushort_t* __restrict__ H, const int* __restrict__ gid,
    float* __restrict__ pooled, float* __restrict__ counts, int n) {
  int wid = (blockIdx.x * blockDim.x + threadIdx.x) >> 6;
  int j = threadIdx.x & 63;
  int s = wid * PCHUNK;
  if (s >= n) return;
  int e = min(s + PCHUNK, n);
  float acc = 0.0f;
  int cur = gid[s];
  int runlen = 0;
  for (int node = s; node < e; ++node) {
    int g = gid[node];
    if (g != cur) {
      atomicAdd(&pooled[cur * 64 + j], acc);
      if (j == 0) atomicAdd(&counts[cur], (float)runlen);
      acc = 0.0f;
      runlen = 0;
      cur = g;
    }
    acc += bflo((uint_t)H[(size_t)node * 64 + j]);
    ++runlen;
  }
  atomicAdd(&pooled[cur * 64 + j], acc);
  if (j == 0) atomicAdd(&counts[cur], (float)runlen);
}

// ---------------------------------------------------------------------------
// 7. MLP head
// ---------------------------------------------------------------------------
__global__ __launch_bounds__(256) void mlp_kernel(
    const float* __restrict__ pooled, const float* __restrict__ counts,
    const float* __restrict__ Dw1, const float* __restrict__ Db1,
    const float* __restrict__ Dw2, const float* __restrict__ Db2,
    const float* __restrict__ Dw3, const float* __restrict__ Db3,
    float* __restrict__ out) {
  int g = blockIdx.x * blockDim.x + threadIdx.x;
  if (g < G_GRAPHS) {
    float inv = 1.0f / fmaxf(counts[g], 1.0f);
    float p[64];
#pragma unroll
    for (int k = 0; k < 64; ++k) p[k] = pooled[g * 64 + k] * inv;
    float h1[16];
#pragma unroll
    for (int o = 0; o < 16; ++o) {
      float a = Db1[o];
      for (int k = 0; k < 64; ++k) a = fmaf(p[k], Dw1[k * 16 + o], a);
      h1[o] = fmaxf(a, 0.0f);
    }
    float h2[8];
#pragma unroll
    for (int o = 0; o < 8; ++o) {
      float a = Db2[o];
      for (int k = 0; k < 16; ++k) a = fmaf(h1[k], Dw2[k * 8 + o], a);
      h2[o] = fmaxf(a, 0.0f);
    }
    float a = Db3[0];
#pragma unroll
    for (int k = 0; k < 8; ++k) a = fmaf(h2[k], Dw3[k], a);
    out[g] = 1.0f / (1.0f + expf(-a));
  }
}

// ---------------------------------------------------------------------------
extern "C" void kernel_launch(void* const* d_in, const int* in_sizes, int n_in,
                              void* d_out, int out_size, void* d_ws, size_t ws_size,
                              hipStream_t stream) {
  const float* x   = (const float*)d_in[0];
  const int*   src = (const int*)  d_in[1];
  const int*   dst = (const int*)  d_in[2];
  const float* ew  = (const float*)d_in[3];
  const int*   gid = (const int*)  d_in[4];
  const float* W1  = (const float*)d_in[5];
  const float* b1  = (const float*)d_in[6];
  const float* W2  = (const float*)d_in[7];
  const float* b2  = (const float*)d_in[8];
  const float* W3  = (const float*)d_in[9];
  const float* b3  = (const float*)d_in[10];
  const float* Dw1 = (const float*)d_in[11];
  const float* Db1 = (const float*)d_in[12];
  const float* Dw2 = (const float*)d_in[13];
  const float* Db2 = (const float*)d_in[14];
  const float* Dw3 = (const float*)d_in[15];
  const float* Db3 = (const float*)d_in[16];
  float* out = (float*)d_out;

  // workspace layout (16B-aligned regions)
  char* ws = (char*)d_ws;
  ushort_t* Tb   = (ushort_t*)ws;                       // N*64 bf16
  ushort_t* Hb   = Tb + (size_t)N_NODES * 64;           // N*64 bf16
  float* ns      = (float*)(Hb + (size_t)N_NODES * 64); // N
  float* nd      = ns + N_NODES;                        // N
  float* pooled  = nd + N_NODES;                        // G*64
  float* counts  = pooled + G_GRAPHS * 64;              // G
  int*   cnt_out = (int*)(counts + G_GRAPHS);           // N (also cursor)
  int*   cnt_in  = cnt_out + N_NODES;                   // N
  int*   row_ptr = cnt_in + N_NODES;                    // N
  int*   bsums   = row_ptr + N_NODES;                   // 128
  uint2* csr     = (uint2*)(bsums + 128);               // E (8B each)

  const int NB_E    = (N_EDGES + 255) / 256;
  const int NB_N    = (N_NODES + 255) / 256;
  const int NB_SCAN = (N_NODES + SCAN_CH - 1) / SCAN_CH;
  const int NB_GEMM = (N_NODES + 31) / 32;
  const int NB_GATH = (N_NODES * 64 + 255) / 256;
  const int NB_POOL = (PWAVES * 64) / 256;

  // ---- degrees, norms, CSR build
  hipMemsetAsync(cnt_out, 0, 2ull * N_NODES * sizeof(int), stream);
  hist_kernel<<<NB_E, 256, 0, stream>>>(src, dst, cnt_out, cnt_in, N_EDGES);
  norm_kernel<<<NB_N, 256, 0, stream>>>(cnt_out, cnt_in, ns, nd, N_NODES);
  scanA_kernel<<<NB_SCAN, 256, 0, stream>>>(cnt_in, row_ptr, bsums, N_NODES);
  scanB_kernel<<<1, 256, 0, stream>>>(bsums, NB_SCAN);
  scanC_kernel<<<NB_N, 256, 0, stream>>>(row_ptr, bsums, N_NODES);
  hipMemsetAsync(cnt_out, 0, (size_t)N_NODES * sizeof(int), stream);  // cursor
  place_kernel<<<NB_E, 256, 0, stream>>>(src, dst, ew, row_ptr, cnt_out, csr, N_EDGES);

  // ---- layer 1: x(fp32,128) -> Tb -> Hb
  gemm_kernel<IN_F, false><<<NB_GEMM, 256, 0, stream>>>(x, W1, ns, Tb, N_NODES);
  gather_kernel<<<NB_GATH, 256, 0, stream>>>(csr, row_ptr, cnt_in, Tb, nd, b1, Hb, N_NODES);
  // ---- layer 2
  gemm_kernel<H_F, true><<<NB_GEMM, 256, 0, stream>>>(Hb, W2, ns, Tb, N_NODES);
  gather_kernel<<<NB_GATH, 256, 0, stream>>>(csr, row_ptr, cnt_in, Tb, nd, b2, Hb, N_NODES);
  // ---- layer 3
  gemm_kernel<H_F, true><<<NB_GEMM, 256, 0, stream>>>(Hb, W3, ns, Tb, N_NODES);
  gather_kernel<<<NB_GATH, 256, 0, stream>>>(csr, row_ptr, cnt_in, Tb, nd, b3, Hb, N_NODES);

  // ---- pool + MLP
  hipMemsetAsync(pooled, 0, (size_t)(G_GRAPHS * 64 + G_GRAPHS) * sizeof(float), stream);
  pool_seg_kernel<<<NB_POOL, 256, 0, stream>>>(Hb, gid, pooled, counts, N_NODES);
  mlp_kernel<<<1, 256, 0, stream>>>(pooled, counts, Dw1, Db1, Dw2, Db2, Dw3, Db3, out);
}

// Round 4
// 486.397 us; speedup vs baseline: 4.0433x; 1.6978x over previous
//
#include <hip/hip_runtime.h>
#include <math.h>

#define N_NODES 100000
#define N_EDGES 1600000
#define G_GRAPHS 256
#define IN_F 128
#define H_F 64

#define SCAN_CH 1024
#define PWAVES 1024
#define PCHUNK ((N_NODES + PWAVES - 1) / PWAVES)

// histogram partitioning
#define HRANGE 16384           // nodes per LDS sub-histogram (64 KB)
#define HR 7                   // ranges: 7*16384 = 114688 >= 100000
#define HB 20                  // edge-chunk blocks per (array,range)
#define HCHUNK (N_EDGES / HB)  // 80000, divisible by 4

typedef unsigned int uint_t;
typedef unsigned short ushort_t;
typedef __attribute__((ext_vector_type(8))) short short8;
typedef __attribute__((ext_vector_type(4))) float floatx4;

__device__ __forceinline__ ushort_t f2bf(float f) {  // round-to-nearest-even
  uint_t u = __float_as_uint(f);
  uint_t r = (u + 0x7fffu + ((u >> 16) & 1u)) >> 16;
  return (ushort_t)r;
}
__device__ __forceinline__ float bflo(uint_t u) { return __uint_as_float(u << 16); }
__device__ __forceinline__ float bfhi(uint_t u) { return __uint_as_float(u & 0xffff0000u); }

// ---------------------------------------------------------------------------
// 1. LDS-privatized degree histograms -> per-block partials (no global atomics)
//    grid = 2 arrays * HR ranges * HB blocks = 280
// ---------------------------------------------------------------------------
__global__ __launch_bounds__(256) void hist_kernel(
    const int* __restrict__ src, const int* __restrict__ dst,
    int* __restrict__ partials /* [2][HB][N_NODES] */) {
  __shared__ int hist[HRANGE];
  const int a = blockIdx.x / (HR * HB);
  const int rem = blockIdx.x % (HR * HB);
  const int r = rem / HB;
  const int b = rem % HB;
  const int base = r * HRANGE;
  const int width = min(base + HRANGE, N_NODES) - base;

  for (int i = threadIdx.x; i < HRANGE; i += 256) hist[i] = 0;
  __syncthreads();

  const int* keys = a ? dst : src;
  const uint4* k4 = (const uint4*)(keys + b * HCHUNK);
  for (int i = threadIdx.x; i < HCHUNK / 4; i += 256) {
    uint4 v = k4[i];
    int t;
    t = (int)v.x - base; if ((unsigned)t < (unsigned)width) atomicAdd(&hist[t], 1);
    t = (int)v.y - base; if ((unsigned)t < (unsigned)width) atomicAdd(&hist[t], 1);
    t = (int)v.z - base; if ((unsigned)t < (unsigned)width) atomicAdd(&hist[t], 1);
    t = (int)v.w - base; if ((unsigned)t < (unsigned)width) atomicAdd(&hist[t], 1);
  }
  __syncthreads();

  int* outp = partials + ((size_t)a * HB + b) * N_NODES + base;
  for (int i = threadIdx.x; i < width; i += 256) outp[i] = hist[i];
}

// reduce partials -> cnt_out/cnt_in + fused ns/nd
__global__ __launch_bounds__(256) void hist_reduce_kernel(
    const int* __restrict__ partials, int* __restrict__ cnt_out,
    int* __restrict__ cnt_in, float* __restrict__ ns, float* __restrict__ nd) {
  int i = blockIdx.x * blockDim.x + threadIdx.x;
  if (i >= 2 * N_NODES) return;
  int a = i / N_NODES, node = i % N_NODES;
  const int* p = partials + (size_t)a * HB * N_NODES + node;
  int s = 0;
#pragma unroll
  for (int b = 0; b < HB; ++b) s += p[(size_t)b * N_NODES];
  float nrm = rsqrtf(fmaxf((float)s, 1.0f));
  if (a == 0) { cnt_out[node] = s; ns[node] = nrm; }
  else        { cnt_in[node] = s;  nd[node] = nrm; }
}

// ---------------------------------------------------------------------------
// 2. Exclusive scan of cnt_in -> row_ptr
// ---------------------------------------------------------------------------
__global__ __launch_bounds__(256) void scanA_kernel(
    const int* __restrict__ in, int* __restrict__ out, int* __restrict__ bsums, int n) {
  __shared__ int ts[256];
  const int tid = threadIdx.x;
  const int base = blockIdx.x * SCAN_CH + tid * 4;
  int v[4], pre[4], s = 0;
#pragma unroll
  for (int k = 0; k < 4; ++k) {
    v[k] = (base + k < n) ? in[base + k] : 0;
    pre[k] = s;
    s += v[k];
  }
  ts[tid] = s;
  __syncthreads();
  for (int off = 1; off < 256; off <<= 1) {
    int t = (tid >= off) ? ts[tid - off] : 0;
    __syncthreads();
    ts[tid] += t;
    __syncthreads();
  }
  int excl = (tid == 0) ? 0 : ts[tid - 1];
#pragma unroll
  for (int k = 0; k < 4; ++k)
    if (base + k < n) out[base + k] = excl + pre[k];
  if (tid == 255) bsums[blockIdx.x] = ts[255];
}

__global__ __launch_bounds__(256) void scanB_kernel(int* __restrict__ bsums, int nb) {
  __shared__ int ts[256];
  const int tid = threadIdx.x;
  ts[tid] = (tid < nb) ? bsums[tid] : 0;
  __syncthreads();
  for (int off = 1; off < 256; off <<= 1) {
    int t = (tid >= off) ? ts[tid - off] : 0;
    __syncthreads();
    ts[tid] += t;
    __syncthreads();
  }
  if (tid < nb) bsums[tid] = (tid == 0) ? 0 : ts[tid - 1];
}

__global__ __launch_bounds__(256) void scanC_kernel(
    int* __restrict__ out, const int* __restrict__ bsums, int n) {
  int i = blockIdx.x * blockDim.x + threadIdx.x;
  if (i < n) out[i] += bsums[i / SCAN_CH];
}

// ---------------------------------------------------------------------------
// 3. Edge placement into CSR (dst-major), fused (src, weight) uint2
// ---------------------------------------------------------------------------
__global__ __launch_bounds__(256) void place_kernel(
    const int* __restrict__ src, const int* __restrict__ dst,
    const float* __restrict__ ew, const int* __restrict__ row_ptr,
    int* __restrict__ cursor, uint2* __restrict__ csr, int E) {
  int e = blockIdx.x * blockDim.x + threadIdx.x;
  if (e < E) {
    int d = dst[e];
    int slot = row_ptr[d] + atomicAdd(&cursor[d], 1);
    csr[slot] = make_uint2((uint_t)src[e], __float_as_uint(ew[e]));
  }
}

// ---------------------------------------------------------------------------
// 4. MFMA GEMM: T[i,:] = bf16(ns[i] * (X[i,:] @ W))
//    one wave per 16-node tile; 4 n-tiles of 16 feats; K/32 chunks.
//    A-frag: lane m=lane&15 row, k=(lane>>4)*8..+8 -> 16B contiguous loads.
//    B-frag from LDS (W transposed to bf16).
//    C/D: col=lane&15 (feature), row=(lane>>4)*4+reg (node)  [m89/m91 layout]
// ---------------------------------------------------------------------------
template <int K, bool AFP32>
__global__ __launch_bounds__(256) void gemm_mfma_kernel(
    const void* __restrict__ Xin, const float* __restrict__ W,
    const float* __restrict__ ns, ushort_t* __restrict__ T, int ntiles) {
  constexpr int CH = K / 32;
  constexpr int WROW = K + 8;  // pad, keeps rows 16B-aligned
  __shared__ __align__(16) ushort_t Wt[64 * WROW];
  const int tid = threadIdx.x;

  // stage W^T as bf16: Wt[n][k] = bf16(W[k*64+n])
  for (int i = tid; i < K * 64; i += 256) {
    int k = i >> 6, nn = i & 63;
    Wt[nn * WROW + k] = f2bf(W[i]);
  }
  __syncthreads();

  const int wave = tid >> 6;
  const int lane = tid & 63;
  const int tile = blockIdx.x * 4 + wave;
  if (tile >= ntiles) return;
  const int m = lane & 15;   // A row (node) / B col (feature)
  const int q = lane >> 4;   // k-octet selector
  const int node0 = tile * 16;

  short8 afrag[CH];
  if (AFP32) {
    const float* xr = (const float*)Xin + (size_t)(node0 + m) * K + q * 8;
#pragma unroll
    for (int c = 0; c < CH; ++c) {
      float4 xa = *(const float4*)(xr + c * 32);
      float4 xb = *(const float4*)(xr + c * 32 + 4);
      short8 a;
      a[0] = (short)f2bf(xa.x); a[1] = (short)f2bf(xa.y);
      a[2] = (short)f2bf(xa.z); a[3] = (short)f2bf(xa.w);
      a[4] = (short)f2bf(xb.x); a[5] = (short)f2bf(xb.y);
      a[6] = (short)f2bf(xb.z); a[7] = (short)f2bf(xb.w);
      afrag[c] = a;
    }
  } else {
    const ushort_t* xr = (const ushort_t*)Xin + (size_t)(node0 + m) * K + q * 8;
#pragma unroll
    for (int c = 0; c < CH; ++c)
      afrag[c] = *(const short8*)(xr + c * 32);
  }

  floatx4 acc[4];
#pragma unroll
  for (int t = 0; t < 4; ++t) acc[t] = (floatx4){0.f, 0.f, 0.f, 0.f};

#pragma unroll
  for (int t = 0; t < 4; ++t) {
    const ushort_t* wr = &Wt[(t * 16 + m) * WROW + q * 8];
#pragma unroll
    for (int c = 0; c < CH; ++c) {
      short8 bfrag = *(const short8*)(wr + c * 32);
      acc[t] = __builtin_amdgcn_mfma_f32_16x16x32_bf16(afrag[c], bfrag, acc[t], 0, 0, 0);
    }
  }

  float4 nsv = *(const float4*)(ns + node0 + q * 4);
  const float nsa[4] = {nsv.x, nsv.y, nsv.z, nsv.w};
#pragma unroll
  for (int t = 0; t < 4; ++t) {
#pragma unroll
    for (int r = 0; r < 4; ++r) {
      int node = node0 + q * 4 + r;
      T[(size_t)node * 64 + t * 16 + m] = f2bf(acc[t][r] * nsa[r]);
    }
  }
}

// ---------------------------------------------------------------------------
// 5. CSR gather (bf16 T), 8 edges in flight per wave-iteration.
// ---------------------------------------------------------------------------
__global__ __launch_bounds__(256) void gather_kernel(
    const uint2* __restrict__ csr, const int* __restrict__ row_ptr,
    const int* __restrict__ cnt_in, const ushort_t* __restrict__ T,
    const float* __restrict__ nd, const float* __restrict__ b,
    ushort_t* __restrict__ H, int n) {
  int id = blockIdx.x * blockDim.x + threadIdx.x;
  int v = id >> 6;
  if (v >= n) return;
  const int lane = threadIdx.x & 63;
  const int g = lane >> 3, l = lane & 7;
  const int start = row_ptr[v];
  const int cnt = cnt_in[v];

  float acc[8] = {0, 0, 0, 0, 0, 0, 0, 0};
  for (int k = 0; k < cnt; k += 8) {
    int idx = k + g;
    uint2 e = csr[start + min(idx, cnt - 1)];
    float w = (idx < cnt) ? __uint_as_float(e.y) : 0.0f;
    uint4 p = *((const uint4*)(T + (size_t)e.x * 64) + l);
    acc[0] = fmaf(bflo(p.x), w, acc[0]);
    acc[1] = fmaf(bfhi(p.x), w, acc[1]);
    acc[2] = fmaf(bflo(p.y), w, acc[2]);
    acc[3] = fmaf(bfhi(p.y), w, acc[3]);
    acc[4] = fmaf(bflo(p.z), w, acc[4]);
    acc[5] = fmaf(bfhi(p.z), w, acc[5]);
    acc[6] = fmaf(bflo(p.w), w, acc[6]);
    acc[7] = fmaf(bfhi(p.w), w, acc[7]);
  }
#pragma unroll
  for (int off = 8; off < 64; off <<= 1) {
#pragma unroll
    for (int i = 0; i < 8; ++i) acc[i] += __shfl_xor(acc[i], off, 64);
  }
  if (g == 0) {
    float ndv = nd[v];
    float4 b0 = *(const float4*)&b[l * 8];
    float4 b1 = *(const float4*)&b[l * 8 + 4];
    uint4 o;
    o.x = (uint_t)f2bf(fmaxf(fmaf(acc[0], ndv, b0.x), 0.f)) |
          ((uint_t)f2bf(fmaxf(fmaf(acc[1], ndv, b0.y), 0.f)) << 16);
    o.y = (uint_t)f2bf(fmaxf(fmaf(acc[2], ndv, b0.z), 0.f)) |
          ((uint_t)f2bf(fmaxf(fmaf(acc[3], ndv, b0.w), 0.f)) << 16);
    o.z = (uint_t)f2bf(fmaxf(fmaf(acc[4], ndv, b1.x), 0.f)) |
          ((uint_t)f2bf(fmaxf(fmaf(acc[5], ndv, b1.y), 0.f)) << 16);
    o.w = (uint_t)f2bf(fmaxf(fmaf(acc[6], ndv, b1.z), 0.f)) |
          ((uint_t)f2bf(fmaxf(fmaf(acc[7], ndv, b1.w), 0.f)) << 16);
    *((uint4*)(H + (size_t)v * 64) + l) = o;
  }
}

// ---------------------------------------------------------------------------
// 6. Segmented pool over sorted gid (bf16 H)
// ---------------------------------------------------------------------------
__global__ __launch_bounds__(256) void pool_seg_kernel(
    const ushort_t* __restrict__ H, const int* __restrict__ gid,
    float* __restrict__ pooled, float* __restrict__ counts, int n) {
  int wid = (blockIdx.x * blockDim.x + threadIdx.x) >> 6;
  int j = threadIdx.x & 63;
  int s = wid * PCHUNK;
  if (s >= n) return;
  int e = min(s + PCHUNK, n);
  float acc = 0.0f;
  int cur = gid[s];
  int runlen = 0;
  for (int node = s; node < e; ++node) {
    int g = gid[node];
    if (g != cur) {
      atomicAdd(&pooled[cur * 64 + j], acc);
      if (j == 0) atomicAdd(&counts[cur], (float)runlen);
      acc = 0.0f;
      runlen = 0;
      cur = g;
    }
    acc += bflo((uint_t)H[(size_t)node * 64 + j]);
    ++runlen;
  }
  atomicAdd(&pooled[cur * 64 + j], acc);
  if (j == 0) atomicAdd(&counts[cur], (float)runlen);
}

// ---------------------------------------------------------------------------
// 7. MLP head
// ---------------------------------------------------------------------------
__global__ __launch_bounds__(256) void mlp_kernel(
    const float* __restrict__ pooled, const float* __restrict__ counts,
    const float* __restrict__ Dw1, const float* __restrict__ Db1,
    const float* __restrict__ Dw2, const float* __restrict__ Db2,
    const float* __restrict__ Dw3, const float* __restrict__ Db3,
    float* __restrict__ out) {
  int g = blockIdx.x * blockDim.x + threadIdx.x;
  if (g < G_GRAPHS) {
    float inv = 1.0f / fmaxf(counts[g], 1.0f);
    float p[64];
#pragma unroll
    for (int k = 0; k < 64; ++k) p[k] = pooled[g * 64 + k] * inv;
    float h1[16];
#pragma unroll
    for (int o = 0; o < 16; ++o) {
      float a = Db1[o];
      for (int k = 0; k < 64; ++k) a = fmaf(p[k], Dw1[k * 16 + o], a);
      h1[o] = fmaxf(a, 0.0f);
    }
    float h2[8];
#pragma unroll
    for (int o = 0; o < 8; ++o) {
      float a = Db2[o];
      for (int k = 0; k < 16; ++k) a = fmaf(h1[k], Dw2[k * 8 + o], a);
      h2[o] = fmaxf(a, 0.0f);
    }
    float a = Db3[0];
#pragma unroll
    for (int k = 0; k < 8; ++k) a = fmaf(h2[k], Dw3[k], a);
    out[g] = 1.0f / (1.0f + expf(-a));
  }
}

// ---------------------------------------------------------------------------
extern "C" void kernel_launch(void* const* d_in, const int* in_sizes, int n_in,
                              void* d_out, int out_size, void* d_ws, size_t ws_size,
                              hipStream_t stream) {
  const float* x   = (const float*)d_in[0];
  const int*   src = (const int*)  d_in[1];
  const int*   dst = (const int*)  d_in[2];
  const float* ew  = (const float*)d_in[3];
  const int*   gid = (const int*)  d_in[4];
  const float* W1  = (const float*)d_in[5];
  const float* b1  = (const float*)d_in[6];
  const float* W2  = (const float*)d_in[7];
  const float* b2  = (const float*)d_in[8];
  const float* W3  = (const float*)d_in[9];
  const float* b3  = (const float*)d_in[10];
  const float* Dw1 = (const float*)d_in[11];
  const float* Db1 = (const float*)d_in[12];
  const float* Dw2 = (const float*)d_in[13];
  const float* Db2 = (const float*)d_in[14];
  const float* Dw3 = (const float*)d_in[15];
  const float* Db3 = (const float*)d_in[16];
  float* out = (float*)d_out;

  // workspace layout
  char* ws = (char*)d_ws;
  ushort_t* Tb   = (ushort_t*)ws;                       // N*64 bf16
  ushort_t* Hb   = Tb + (size_t)N_NODES * 64;           // N*64 bf16
  float* ns      = (float*)(Hb + (size_t)N_NODES * 64); // N
  float* nd      = ns + N_NODES;                        // N
  float* pooled  = nd + N_NODES;                        // G*64
  float* counts  = pooled + G_GRAPHS * 64;              // G
  int*   cnt_out = (int*)(counts + G_GRAPHS);           // N (also cursor)
  int*   cnt_in  = cnt_out + N_NODES;                   // N
  int*   row_ptr = cnt_in + N_NODES;                    // N
  int*   bsums   = row_ptr + N_NODES;                   // 128
  uint2* csr     = (uint2*)(bsums + 128);               // E (8B each)
  // partials alias Tb/Hb (dead before gemm1 runs): 2*HB*N ints = 16 MB <= 25.6 MB
  int*   partials = (int*)Tb;

  const int NTILES  = N_NODES / 16;                     // 6250 (exact)
  const int NB_E    = (N_EDGES + 255) / 256;
  const int NB_N    = (N_NODES + 255) / 256;
  const int NB_SCAN = (N_NODES + SCAN_CH - 1) / SCAN_CH;
  const int NB_HIST = 2 * HR * HB;                      // 280
  const int NB_RED  = (2 * N_NODES + 255) / 256;
  const int NB_GEMM = (NTILES + 3) / 4;                 // 1563
  const int NB_GATH = (N_NODES * 64 + 255) / 256;
  const int NB_POOL = (PWAVES * 64) / 256;

  // ---- degrees (privatized hist), norms, CSR build
  hist_kernel<<<NB_HIST, 256, 0, stream>>>(src, dst, partials);
  hist_reduce_kernel<<<NB_RED, 256, 0, stream>>>(partials, cnt_out, cnt_in, ns, nd);
  scanA_kernel<<<NB_SCAN, 256, 0, stream>>>(cnt_in, row_ptr, bsums, N_NODES);
  scanB_kernel<<<1, 256, 0, stream>>>(bsums, NB_SCAN);
  scanC_kernel<<<NB_N, 256, 0, stream>>>(row_ptr, bsums, N_NODES);
  hipMemsetAsync(cnt_out, 0, (size_t)N_NODES * sizeof(int), stream);  // cursor
  place_kernel<<<NB_E, 256, 0, stream>>>(src, dst, ew, row_ptr, cnt_out, csr, N_EDGES);

  // ---- layer 1: x(fp32,128) -> Tb -> Hb
  gemm_mfma_kernel<IN_F, true><<<NB_GEMM, 256, 0, stream>>>(x, W1, ns, Tb, NTILES);
  gather_kernel<<<NB_GATH, 256, 0, stream>>>(csr, row_ptr, cnt_in, Tb, nd, b1, Hb, N_NODES);
  // ---- layer 2
  gemm_mfma_kernel<H_F, false><<<NB_GEMM, 256, 0, stream>>>(Hb, W2, ns, Tb, NTILES);
  gather_kernel<<<NB_GATH, 256, 0, stream>>>(csr, row_ptr, cnt_in, Tb, nd, b2, Hb, N_NODES);
  // ---- layer 3
  gemm_mfma_kernel<H_F, false><<<NB_GEMM, 256, 0, stream>>>(Hb, W3, ns, Tb, NTILES);
  gather_kernel<<<NB_GATH, 256, 0, stream>>>(csr, row_ptr, cnt_in, Tb, nd, b3, Hb, N_NODES);

  // ---- pool + MLP
  hipMemsetAsync(pooled, 0, (size_t)(G_GRAPHS * 64 + G_GRAPHS) * sizeof(float), stream);
  pool_seg_kernel<<<NB_POOL, 256, 0, stream>>>(Hb, gid, pooled, counts, N_NODES);
  mlp_kernel<<<1, 256, 0, stream>>>(pooled, counts, Dw1, Db1, Dw2, Db2, Dw3, Db3, out);
}